// Round 3
// baseline (35588.840 us; speedup 1.0000x reference)
//
#include <hip/hip_runtime.h>
#include <stdint.h>

// ============================================================================
// RNNModel: emb-lookup -> BiGRU(E=128->H=256) -> BiGRU(512->256) -> MLP+BN ->
//           dense(61) -> softmax + mask.   B=64, S=2048, H=256, V=61.
//
// ws_size is 256 MiB (measured round 2: poison fill WRITE_SIZE=262144 KB).
// h2 is NEVER materialized: layer-1 scan emits per-chunk fwd/bwd hidden
// chunks in scan order; y1pre (bf16) accumulates out_f@W1f^T (+b1, row s=t)
// and out_b@W1b^T (row s=len-1-t, predicated for s<0).
// Peak @TC=256: 3.68 + 128(h1) + 32(y1pre) + 48(gi) + 16(hc) = 238.6 MiB.
// ============================================================================

#define SS 2048
#define NEGV -1000000000.0f

__device__ __forceinline__ float bf2f(unsigned short u) {
    union { unsigned int i; float f; } v; v.i = ((unsigned int)u) << 16; return v.f;
}
__device__ __forceinline__ unsigned short f2bf(float f) {
    union { float f; unsigned int i; } v; v.f = f;
    unsigned int i = v.i;
    return (unsigned short)((i + 0x7fffu + ((i >> 16) & 1u)) >> 16);
}
__device__ __forceinline__ float2 bfpair(unsigned int u) {
    union { unsigned int i; float f; } a, b;
    a.i = u << 16; b.i = u & 0xffff0000u;
    float2 r; r.x = a.f; r.y = b.f; return r;
}

// ---------------------------------------------------------------------------
__global__ void zero_stats_kernel(float* st) {
    st[blockIdx.x*256 + threadIdx.x] = 0.0f;   // 4 x 256 = 1024 floats
}

__global__ void init_y1_kernel(unsigned short* y1, const float* b1) {
    size_t total = 131072ull*128;
    for (size_t i = blockIdx.x*(size_t)blockDim.x + threadIdx.x; i < total;
         i += (size_t)gridDim.x*blockDim.x)
        y1[i] = f2bf(b1[i & 127]);
}

// ---------------------------------------------------------------------------
// Prep: layer0 gi token tables, bf16 weight packs, bias folds.
// w123 layout: w1f[128x256] | w1b[128x256] | w2[256x128] | w3[128x256]
// ---------------------------------------------------------------------------
__global__ void prep_kernel(
    const float* emb,
    const float* wih0f, const float* bih0f, const float* bhh0f,
    const float* wih0b, const float* bih0b, const float* bhh0b,
    const float* whh0f, const float* whh0b, const float* whh1f, const float* whh1b,
    const float* wih1f, const float* wih1b,
    const float* bih1f, const float* bhh1f, const float* bih1b, const float* bhh1b,
    const float* w1, const float* w2, const float* w3,
    float* T0, unsigned short* wpk, unsigned short* wih1bf, unsigned short* w123,
    float* bias1, float* bhn)
{
    const int NA = 2*21*768;      // T0 entries (each = 128-dot)
    const int NB = 4*64*768;      // wpk ushort4 entries
    const int NC = 2*768*512;     // wih1 bf16
    const int ND = 131072;        // w1f|w1b|w2|w3 bf16
    const int NE = 2*768 + 4*256; // bias1 + bhn
    int total = NA + NB + NC + ND + NE;
    for (int idx = blockIdx.x*blockDim.x + threadIdx.x; idx < total;
         idx += gridDim.x*blockDim.x) {
        int i = idx;
        if (i < NA) {
            int d = i / (21*768); int rem = i % (21*768);
            int v = rem / 768; int j = rem % 768;
            const float* wih = d ? wih0b : wih0f;
            const float* bih = d ? bih0b : bih0f;
            const float* bhh = d ? bhh0b : bhh0f;
            float s = bih[j] + (j < 512 ? bhh[j] : 0.0f);
            const float* er = emb + v*128;
            const float* wr = wih + j*128;
            for (int e = 0; e < 128; e++) s += er[e]*wr[e];
            T0[i] = s;
            continue;
        }
        i -= NA;
        if (i < NB) {
            int dl = i / (64*768); int rem = i % (64*768);
            int k4 = rem / 768; int j = rem % 768;
            const float* whh = dl==0 ? whh0f : dl==1 ? whh0b : dl==2 ? whh1f : whh1b;
            unsigned short* dst = wpk + (size_t)i*4;
            for (int q = 0; q < 4; q++) dst[q] = f2bf(whh[j*256 + k4*4 + q]);
            continue;
        }
        i -= NB;
        if (i < NC) {
            int d = i / (768*512); int rem = i % (768*512);
            const float* w = d ? wih1b : wih1f;
            wih1bf[i] = f2bf(w[rem]);
            continue;
        }
        i -= NC;
        if (i < ND) {
            float v;
            if (i < 32768)       { int n = i >> 8, k = i & 255; v = w1[n*512 + k]; }
            else if (i < 65536)  { int r = i - 32768; int n = r >> 8, k = r & 255; v = w1[n*512 + 256 + k]; }
            else if (i < 98304)  v = w2[i - 65536];
            else                 v = w3[i - 98304];
            w123[i] = f2bf(v);
            continue;
        }
        i -= ND;
        if (i < 2*768) {
            int d = i / 768; int j = i % 768;
            const float* bih = d ? bih1b : bih1f;
            const float* bhh = d ? bhh1b : bhh1f;
            bias1[i] = bih[j] + (j < 512 ? bhh[j] : 0.0f);
            continue;
        }
        i -= 2*768;
        {
            int dl = i / 256; int j = i % 256;
            const float* bhh = dl==0 ? bhh0f : dl==1 ? bhh0b : dl==2 ? bhh1f : bhh1b;
            bhn[i] = bhh[512 + j];
        }
    }
}

// ---------------------------------------------------------------------------
// GRU scan over [t0, t0+steps). One block per (dir, batch). h in LDS,
// persisted via hstate across chunks. Layer 0: token-table gi, writes full
// h1 with bwd reversal. Layer 1: chunk gi buffers, writes scan-order chunks.
// ---------------------------------------------------------------------------
__global__ __launch_bounds__(256) void scan_kernel(
    const int* x, const int* lens, const float* T0,
    const unsigned short* gi_f, const unsigned short* gi_b,
    const unsigned short* wpk, const float* bhn, float* hstate,
    unsigned short* outFull, unsigned short* outF, unsigned short* outB,
    int layer, int t0, int steps, int first)
{
    __shared__ __align__(16) float hs[256];
    int b   = blockIdx.x & 63;
    int dir = blockIdx.x >> 6;
    int j   = threadIdx.x;
    int len = lens[b];
    int dl  = layer*2 + dir;
    const uint2* wb = (const uint2*)(wpk + (size_t)dl*(64*768*4)) + j;
    float bhn_j = bhn[dl*256 + j];
    const float* T = T0 + (size_t)dir*21*768;
    const unsigned short* gi = dir ? gi_b : gi_f;
    unsigned short* co = dir ? outB : outF;
    const int* xrow = x + b*SS;
    float* hst = hstate + (size_t)(dir*64 + b)*256;

    float hj = first ? 0.0f : hst[j];
    hs[j] = hj;
    __syncthreads();

    int tend = len < t0 + steps ? len : t0 + steps;
    for (int t = t0; t < tend; t++) {
        float gr, gz, gn;
        if (layer == 0) {
            int tok = xrow[dir ? (len-1-t) : t];
            const float* Tr = T + tok*768;
            gr = Tr[j]; gz = Tr[j+256]; gn = Tr[j+512];
        } else {
            const unsigned short* gp = gi + ((size_t)(t - t0)*64 + b)*768;
            gr = bf2f(gp[j]); gz = bf2f(gp[j+256]); gn = bf2f(gp[j+512]);
        }
        float dr = 0.f, dz = 0.f, dn = 0.f;
        #pragma unroll 8
        for (int k4 = 0; k4 < 64; k4++) {
            float4 h4 = ((const float4*)hs)[k4];
            uint2 ur = wb[k4*768];
            uint2 uz = wb[k4*768 + 256];
            uint2 un = wb[k4*768 + 512];
            float2 p;
            p = bfpair(ur.x); dr += h4.x*p.x + h4.y*p.y;
            p = bfpair(ur.y); dr += h4.z*p.x + h4.w*p.y;
            p = bfpair(uz.x); dz += h4.x*p.x + h4.y*p.y;
            p = bfpair(uz.y); dz += h4.z*p.x + h4.w*p.y;
            p = bfpair(un.x); dn += h4.x*p.x + h4.y*p.y;
            p = bfpair(un.y); dn += h4.z*p.x + h4.w*p.y;
        }
        float r = 1.0f / (1.0f + __expf(-(gr + dr)));
        float z = 1.0f / (1.0f + __expf(-(gz + dz)));
        float n = tanhf(gn + r*(dn + bhn_j));
        float hn = (1.0f - z)*n + z*hj;
        __syncthreads();          // everyone done reading hs
        hj = hn;
        hs[j] = hn;
        unsigned short hb = f2bf(hn);
        if (layer == 0) {
            int tout = dir ? (len-1-t) : t;
            outFull[((size_t)b*SS + tout)*512 + dir*256 + j] = hb;
        } else {
            co[((size_t)(t - t0)*64 + b)*256 + j] = hb;
        }
        __syncthreads();          // hs update visible before next step
    }
    hst[j] = hj;
    int zb = len > t0 ? len : t0;
    if (layer == 0) {
        for (int t = zb; t < t0 + steps; t++)
            outFull[((size_t)b*SS + t)*512 + dir*256 + j] = 0;
    } else {
        for (int t = zb; t < t0 + steps; t++)
            co[((size_t)(t - t0)*64 + b)*256 + j] = 0;
    }
}

// ---------------------------------------------------------------------------
// bf16 MFMA GEMM: C[crow(r), n] (+)= A[arow(r), :K] @ W[n, :K]^T + bias.
// amode: 0 r | 1 b*S+(t0+t) | 2 b*S+clamp(len-1-(t0+t),0)   [r=(t<<6)|b]
// cmode: 0 r | 1 b*S+(t0+t) | 2 b*S+(len-1-(t0+t)), store skipped if s<0
// accum: C += (read-modify-write bf16; rows unique per dispatch)
// ---------------------------------------------------------------------------
typedef __attribute__((ext_vector_type(8))) short bf16x8_t;
typedef __attribute__((ext_vector_type(4))) float f32x4_t;

__global__ __launch_bounds__(256) void gemm_kernel(
    const unsigned short* A, const unsigned short* W, const float* bias,
    unsigned short* C, int N, int K, int amode, int cmode, int accum,
    const int* lens, int t0)
{
    int lane = threadIdx.x & 63;
    int wv = threadIdx.x >> 6;
    int n0 = blockIdx.x*64 + wv*16;
    int m0 = blockIdx.y*16;
    int rA = m0 + (lane & 15);
    int arow;
    if (amode == 0) arow = rA;
    else {
        int bb = rA & 63; int t = t0 + (rA >> 6);
        if (amode == 1) arow = bb*SS + t;
        else { int tt = lens[bb] - 1 - t; if (tt < 0) tt = 0; arow = bb*SS + tt; }
    }
    const unsigned short* Ap = A + (size_t)arow*K + (lane >> 4)*8;
    const unsigned short* Wp = W + (size_t)(n0 + (lane & 15))*K + (lane >> 4)*8;
    f32x4_t acc = {0.f, 0.f, 0.f, 0.f};
    for (int k0 = 0; k0 < K; k0 += 32) {
        bf16x8_t a = *(const bf16x8_t*)(Ap + k0);
        bf16x8_t w = *(const bf16x8_t*)(Wp + k0);
        acc = __builtin_amdgcn_mfma_f32_16x16x32_bf16(a, w, acc, 0, 0, 0);
    }
    int n = n0 + (lane & 15);
    float bv = bias ? bias[n] : 0.0f;
    int mbase = m0 + (lane >> 4)*4;
    for (int q = 0; q < 4; q++) {
        int r = mbase + q;
        size_t crow; bool valid = true;
        if (cmode == 0) crow = (size_t)r;
        else {
            int bb = r & 63; int t = t0 + (r >> 6);
            if (cmode == 1) crow = (size_t)bb*SS + t;
            else {
                int s = lens[bb] - 1 - t;
                if (s < 0) { valid = false; crow = 0; }
                else crow = (size_t)bb*SS + s;
            }
        }
        if (valid) {
            float v = acc[q] + bv;
            size_t idx = crow*(size_t)N + n;
            if (accum) v += bf2f(C[idx]);
            C[idx] = f2bf(v);
        }
    }
}

// ---------------------------------------------------------------------------
// BatchNorm stats (sum, sumsq per column) and apply(+leaky), in-place bf16
// ---------------------------------------------------------------------------
__global__ void bn_stats_kernel(const unsigned short* y, int N, int nslab, float* st)
{
    int gtid = blockIdx.x*blockDim.x + threadIdx.x;
    int c = gtid % N;
    int slab = gtid / N;
    const int M = 131072;
    float s = 0.f, s2 = 0.f;
    for (int r = slab; r < M; r += nslab) {
        float v = bf2f(y[(size_t)r*N + c]);
        s += v; s2 += v*v;
    }
    atomicAdd(&st[c], s);
    atomicAdd(&st[N + c], s2);
}

__global__ void bn_apply_kernel(unsigned short* y, const float* st,
                                const float* g, const float* be, int N)
{
    const int M = 131072;
    size_t total = (size_t)M*N;
    float invM = 1.0f / M;
    for (size_t i = blockIdx.x*(size_t)blockDim.x + threadIdx.x; i < total;
         i += (size_t)gridDim.x*blockDim.x) {
        int c = (int)(i % N);
        float mean = st[c]*invM;
        float var = fmaxf(st[N + c]*invM - mean*mean, 0.0f);
        float v = bf2f(y[i]);
        v = g[c]*(v - mean)*rsqrtf(var + 1e-5f) + be[c];
        y[i] = f2bf(v >= 0.f ? v : 0.01f*v);
    }
}

// ---------------------------------------------------------------------------
// Final dense(61) + softmax + mask. One wave per (b,t) row.
// ---------------------------------------------------------------------------
__constant__ int c_lo[21] = {0,0,4,10,12,14,16,18,20,24,26,29,35,36,37,39,43,49,53,57,58};
__constant__ int c_hi[21] = {0,4,10,12,14,16,18,20,24,26,29,35,36,37,39,43,49,53,57,58,60};

__global__ __launch_bounds__(256) void out_kernel(
    const unsigned short* o3, const float* w4, const float* b4,
    const int* x, const int* lens, float* out)
{
    __shared__ __align__(16) float w4t[128*64];   // transposed [k][v] padded to 64
    __shared__ float b4s[64];
    for (int i = threadIdx.x; i < 61*128; i += 256) {
        int v = i / 128, k = i % 128;
        w4t[k*64 + v] = w4[i];
    }
    if (threadIdx.x < 64) b4s[threadIdx.x] = threadIdx.x < 61 ? b4[threadIdx.x] : 0.f;
    __syncthreads();
    int wv = threadIdx.x >> 6;
    int lane = threadIdx.x & 63;
    int row = blockIdx.x*4 + wv;
    int b = row >> 11;
    int t = row & 2047;
    const unsigned int* o3r = (const unsigned int*)(o3 + (size_t)row*128);
    float dot;
    if (lane < 61) {
        dot = 0.f;
        for (int k2 = 0; k2 < 64; k2++) {
            float2 p = bfpair(o3r[k2]);
            dot += p.x * w4t[(2*k2)*64 + lane] + p.y * w4t[(2*k2 + 1)*64 + lane];
        }
        dot += b4s[lane];
    } else dot = -1e30f;
    float mx = dot;
    for (int off = 32; off >= 1; off >>= 1) mx = fmaxf(mx, __shfl_xor(mx, off, 64));
    float e = (lane < 61) ? __expf(dot - mx) : 0.f;
    float sm = e;
    for (int off = 32; off >= 1; off >>= 1) sm += __shfl_xor(sm, off, 64);
    float p = e / sm;
    if (lane < 61) {
        int tok = x[row];
        int len = lens[b];
        float maskv = NEGV;
        if (t < len && tok > 0 && lane >= c_lo[tok] && lane < c_hi[tok]) maskv = 0.f;
        out[(size_t)row*61 + lane] = p + maskv;
    }
}

// ---------------------------------------------------------------------------
__global__ void mask_only_kernel(const int* x, const int* lens, float* out)
{
    int row = blockIdx.x*blockDim.x + threadIdx.x;
    if (row >= 64*SS) return;
    int b = row >> 11, t = row & 2047;
    int tok = x[row], len = lens[b];
    float* o = out + (size_t)row*61;
    int lo = c_lo[tok], hi = c_hi[tok];
    for (int v = 0; v < 61; v++) {
        float m = NEGV;
        if (t < len && tok > 0 && v >= lo && v < hi) m = 0.f;
        o[v] = m;
    }
}

// ---------------------------------------------------------------------------
extern "C" void kernel_launch(void* const* d_in, const int* in_sizes, int n_in,
                              void* d_out, int out_size, void* d_ws, size_t ws_size,
                              hipStream_t stream)
{
    (void)in_sizes; (void)n_in; (void)out_size;
    const int*   x     = (const int*)  d_in[0];
    const int*   lens  = (const int*)  d_in[1];
    const float* emb   = (const float*)d_in[2];
    const float* wih0f = (const float*)d_in[3];
    const float* whh0f = (const float*)d_in[4];
    const float* bih0f = (const float*)d_in[5];
    const float* bhh0f = (const float*)d_in[6];
    const float* wih0b = (const float*)d_in[7];
    const float* whh0b = (const float*)d_in[8];
    const float* bih0b = (const float*)d_in[9];
    const float* bhh0b = (const float*)d_in[10];
    const float* wih1f = (const float*)d_in[11];
    const float* whh1f = (const float*)d_in[12];
    const float* bih1f = (const float*)d_in[13];
    const float* bhh1f = (const float*)d_in[14];
    const float* wih1b = (const float*)d_in[15];
    const float* whh1b = (const float*)d_in[16];
    const float* bih1b = (const float*)d_in[17];
    const float* bhh1b = (const float*)d_in[18];
    const float* w1  = (const float*)d_in[19];
    const float* b1  = (const float*)d_in[20];
    const float* g1  = (const float*)d_in[21];
    const float* be1 = (const float*)d_in[22];
    const float* w2  = (const float*)d_in[23];
    const float* b2  = (const float*)d_in[24];
    const float* g2  = (const float*)d_in[25];
    const float* be2 = (const float*)d_in[26];
    const float* w3  = (const float*)d_in[27];
    const float* b3  = (const float*)d_in[28];
    const float* g3  = (const float*)d_in[29];
    const float* be3 = (const float*)d_in[30];
    const float* w4  = (const float*)d_in[31];
    const float* b4  = (const float*)d_in[32];

    // ---- fixed region ----
    char* ws = (char*)d_ws;
    float*          T0     = (float*)(ws + 0);
    unsigned short* wpk    = (unsigned short*)(ws + 129024);
    unsigned short* wih1bf = (unsigned short*)(ws + 1701888);
    unsigned short* w123   = (unsigned short*)(ws + 3274752);
    float*          bias1  = (float*)(ws + 3536896);
    float*          bhn    = (float*)(ws + 3543040);
    float*          stats  = (float*)(ws + 3547136);
    float*          hstate = (float*)(ws + 3551232);
    const size_t OFF_H1  = 3682304;
    const size_t H1SZ    = 134217728ull;          // 64*2048*512 bf16
    const size_t Y1SZ    = 33554432ull;           // 131072*128 bf16
    const size_t OFF_Y1  = OFF_H1 + H1SZ;         // 137,900,032

    // chunk sizes per TC: gi = TC*64*768*2 each, hc = TC*64*256*2 each
    int TC = 0;
    for (int tc = 256; tc >= 32; tc >>= 1) {
        size_t need = OFF_Y1 + Y1SZ + 2ull*tc*64*768*2 + 2ull*tc*64*256*2;
        if (ws_size >= need) { TC = tc; break; }
    }
    if (TC == 0) { mask_only_kernel<<<512, 256, 0, stream>>>(x, lens, (float*)d_out); return; }

    unsigned short* h1    = (unsigned short*)(ws + OFF_H1);
    unsigned short* y1pre = (unsigned short*)(ws + OFF_Y1);
    unsigned short* gi_f  = (unsigned short*)(ws + OFF_Y1 + Y1SZ);
    unsigned short* gi_b  = gi_f + (size_t)TC*64*768;
    unsigned short* hfc   = gi_b + (size_t)TC*64*768;
    unsigned short* hbc   = hfc  + (size_t)TC*64*256;
    unsigned short* y2    = h1;                          // h1 dead after chunk loop
    unsigned short* y3    = (unsigned short*)(ws + OFF_H1 + 67108864ull);

    zero_stats_kernel<<<4, 256, 0, stream>>>(stats);
    prep_kernel<<<1024, 256, 0, stream>>>(emb, wih0f, bih0f, bhh0f, wih0b, bih0b, bhh0b,
        whh0f, whh0b, whh1f, whh1b, wih1f, wih1b, bih1f, bhh1f, bih1b, bhh1b,
        w1, w2, w3, T0, wpk, wih1bf, w123, bias1, bhn);
    init_y1_kernel<<<2048, 256, 0, stream>>>(y1pre, b1);

    // layer 0 scan (token-table gi), full sequence -> h1
    scan_kernel<<<128, 256, 0, stream>>>(x, lens, T0, nullptr, nullptr, wpk, bhn,
                                         hstate, h1, nullptr, nullptr, 0, 0, SS, 1);

    // layer 1 chunks: gi gemms -> scan -> y1 accumulation gemms
    int NCH = SS / TC;
    for (int c = 0; c < NCH; c++) {
        int t0 = c*TC;
        gemm_kernel<<<dim3(12, TC*4), 256, 0, stream>>>(h1, wih1bf, bias1,
            gi_f, 768, 512, 1, 0, 0, lens, t0);
        gemm_kernel<<<dim3(12, TC*4), 256, 0, stream>>>(h1, wih1bf + 768*512, bias1 + 768,
            gi_b, 768, 512, 2, 0, 0, lens, t0);
        scan_kernel<<<128, 256, 0, stream>>>(x, lens, T0, gi_f, gi_b, wpk, bhn,
                                             hstate, nullptr, hfc, hbc, 1, t0, TC, c == 0);
        gemm_kernel<<<dim3(2, TC*4), 256, 0, stream>>>(hfc, w123, nullptr,
            y1pre, 128, 256, 0, 1, 1, lens, t0);
        gemm_kernel<<<dim3(2, TC*4), 256, 0, stream>>>(hbc, w123 + 32768, nullptr,
            y1pre, 128, 256, 0, 2, 1, lens, t0);
    }

    // MLP: BN1 on y1pre, then dense2/BN2, dense3/BN3 (y2,y3 alias dead h1)
    bn_stats_kernel<<<512, 256, 0, stream>>>(y1pre, 128, 1024, stats);
    bn_apply_kernel<<<2048, 256, 0, stream>>>(y1pre, stats, g1, be1, 128);

    gemm_kernel<<<dim3(4, 8192), 256, 0, stream>>>(y1pre, w123 + 65536, b2,
        y2, 256, 128, 0, 0, 0, nullptr, 0);
    bn_stats_kernel<<<512, 256, 0, stream>>>(y2, 256, 512, stats + 256);
    bn_apply_kernel<<<4096, 256, 0, stream>>>(y2, stats + 256, g2, be2, 256);

    gemm_kernel<<<dim3(2, 8192), 256, 0, stream>>>(y2, w123 + 98304, b3,
        y3, 128, 256, 0, 0, 0, nullptr, 0);
    bn_stats_kernel<<<512, 256, 0, stream>>>(y3, 128, 1024, stats + 768);
    bn_apply_kernel<<<2048, 256, 0, stream>>>(y3, stats + 768, g3, be3, 128);

    // final dense(61) + softmax + mask
    out_kernel<<<32768, 256, 0, stream>>>(y3, w4, b4, x, lens, (float*)d_out);
}

// Round 4
// 22545.978 us; speedup vs baseline: 1.5785x; 1.5785x over previous
//
#include <hip/hip_runtime.h>
#include <stdint.h>

// ============================================================================
// RNNModel: emb-lookup -> BiGRU(E=128->H=256) -> BiGRU(512->256) -> MLP+BN ->
//           dense(61) -> softmax + mask.   B=64, S=2048, H=256, V=61.
//
// Round 4: weight-stationary MFMA scan. Grid = 2dir x 4 batch-groups; each
// 512-thread block keeps its dl's full W_hh (768x256 bf16) in VGPRs as MFMA
// B-fragments (48/wave), h (16 batches x 256) in LDS. Per step: 384 MFMAs
// (G = H @ W_hh^T), gate nonlinearity in C-layout lanes, h round-trip via LDS.
// Fragment conventions verified end-to-end in round 3 (absmax 3.4e-3).
// ws (256 MiB): fixed 3.7 + h1 128 + y1pre 32 + gi 50 + hc 17 = 231 MiB.
// ============================================================================

#define SS 2048
#define NEGV -1000000000.0f
#define HPAD 264   // LDS h row stride (bf16): 132 words -> 2-way banks (free)

__device__ __forceinline__ float bf2f(unsigned short u) {
    union { unsigned int i; float f; } v; v.i = ((unsigned int)u) << 16; return v.f;
}
__device__ __forceinline__ unsigned short f2bf(float f) {
    union { float f; unsigned int i; } v; v.f = f;
    unsigned int i = v.i;
    return (unsigned short)((i + 0x7fffu + ((i >> 16) & 1u)) >> 16);
}
__device__ __forceinline__ float2 bfpair(unsigned int u) {
    union { unsigned int i; float f; } a, b;
    a.i = u << 16; b.i = u & 0xffff0000u;
    float2 r; r.x = a.f; r.y = b.f; return r;
}

typedef __attribute__((ext_vector_type(8))) short bf16x8_t;
typedef __attribute__((ext_vector_type(4))) float f32x4_t;

// ---------------------------------------------------------------------------
__global__ void zero_stats_kernel(float* st) {
    st[blockIdx.x*256 + threadIdx.x] = 0.0f;   // 4 x 256 = 1024 floats
}

__global__ void init_y1_kernel(unsigned short* y1, const float* b1) {
    size_t total = 131072ull*128;
    for (size_t i = blockIdx.x*(size_t)blockDim.x + threadIdx.x; i < total;
         i += (size_t)gridDim.x*blockDim.x)
        y1[i] = f2bf(b1[i & 127]);
}

// ---------------------------------------------------------------------------
// Prep: layer0 gi token tables, bf16 weight packs, bias folds.
// whhbf: [dl][768][256] row-major bf16.
// w123 layout: w1f[128x256] | w1b[128x256] | w2[256x128] | w3[128x256]
// ---------------------------------------------------------------------------
__global__ void prep_kernel(
    const float* emb,
    const float* wih0f, const float* bih0f, const float* bhh0f,
    const float* wih0b, const float* bih0b, const float* bhh0b,
    const float* whh0f, const float* whh0b, const float* whh1f, const float* whh1b,
    const float* wih1f, const float* wih1b,
    const float* bih1f, const float* bhh1f, const float* bih1b, const float* bhh1b,
    const float* w1, const float* w2, const float* w3,
    float* T0, unsigned short* whhbf, unsigned short* wih1bf, unsigned short* w123,
    float* bias1, float* bhn)
{
    const int NA = 2*21*768;      // T0 entries (each = 128-dot)
    const int NB = 4*768*256;     // whhbf bf16
    const int NC = 2*768*512;     // wih1 bf16
    const int ND = 131072;        // w1f|w1b|w2|w3 bf16
    const int NE = 2*768 + 4*256; // bias1 + bhn
    int total = NA + NB + NC + ND + NE;
    for (int idx = blockIdx.x*blockDim.x + threadIdx.x; idx < total;
         idx += gridDim.x*blockDim.x) {
        int i = idx;
        if (i < NA) {
            int d = i / (21*768); int rem = i % (21*768);
            int v = rem / 768; int j = rem % 768;
            const float* wih = d ? wih0b : wih0f;
            const float* bih = d ? bih0b : bih0f;
            const float* bhh = d ? bhh0b : bhh0f;
            float s = bih[j] + (j < 512 ? bhh[j] : 0.0f);
            const float* er = emb + v*128;
            const float* wr = wih + j*128;
            for (int e = 0; e < 128; e++) s += er[e]*wr[e];
            T0[i] = s;
            continue;
        }
        i -= NA;
        if (i < NB) {
            int dl = i / 196608; int rem = i % 196608;
            const float* whh = dl==0 ? whh0f : dl==1 ? whh0b : dl==2 ? whh1f : whh1b;
            whhbf[i] = f2bf(whh[rem]);
            continue;
        }
        i -= NB;
        if (i < NC) {
            int d = i / (768*512); int rem = i % (768*512);
            const float* w = d ? wih1b : wih1f;
            wih1bf[i] = f2bf(w[rem]);
            continue;
        }
        i -= NC;
        if (i < ND) {
            float v;
            if (i < 32768)       { int n = i >> 8, k = i & 255; v = w1[n*512 + k]; }
            else if (i < 65536)  { int r = i - 32768; int n = r >> 8, k = r & 255; v = w1[n*512 + 256 + k]; }
            else if (i < 98304)  v = w2[i - 65536];
            else                 v = w3[i - 98304];
            w123[i] = f2bf(v);
            continue;
        }
        i -= ND;
        if (i < 2*768) {
            int d = i / 768; int j = i % 768;
            const float* bih = d ? bih1b : bih1f;
            const float* bhh = d ? bhh1b : bhh1f;
            bias1[i] = bih[j] + (j < 512 ? bhh[j] : 0.0f);
            continue;
        }
        i -= 2*768;
        {
            int dl = i / 256; int j = i % 256;
            const float* bhh = dl==0 ? bhh0f : dl==1 ? bhh0b : dl==2 ? bhh1f : bhh1b;
            bhn[i] = bhh[512 + j];
        }
    }
}

// ---------------------------------------------------------------------------
// Weight-stationary MFMA GRU scan.
// Block = 512 thr (8 waves), grid = 8 (dir*4 + batch-group of 16).
// Wave wv owns gate-tiles {g*16 + 2wv+jt : g in r,z,n ; jt in 0,1}.
// MFMA: D[m=batch16, n=gate16] += A[m,k32] * B[n,k32]; frag conv per round-3:
//   a: lane holds A[m=lane&15][k=quad*8+i]; b: B-row n=lane&15, same k;
//   C/D: row m=quad*4+reg, col n=lane&15.
// ---------------------------------------------------------------------------
__global__ __launch_bounds__(512, 2) void scan_mfma_kernel(
    const int* x, const int* lens, const float* T0,
    const unsigned short* gi_f, const unsigned short* gi_b,
    const unsigned short* whh, const float* bhn, float* hstate,
    unsigned short* h1out, unsigned short* hfc, unsigned short* hbc,
    int layer, int t0, int tc, int first)
{
    __shared__ unsigned short T0s[21*768];
    __shared__ __align__(16) unsigned short hbuf[16*HPAD];
    const int dir = blockIdx.x >> 2;
    const int bg  = blockIdx.x & 3;
    const int tid = threadIdx.x;
    const int wv = tid >> 6, lane = tid & 63;
    const int col = lane & 15, quad = lane >> 4;
    const int dl = layer*2 + dir;
    const int b0 = bg*16;

    if (layer == 0) {
        const float* Ts = T0 + dir*(21*768);
        for (int i = tid; i < 21*768; i += 512) T0s[i] = f2bf(Ts[i]);
    }

    // ---- load weight fragments (VGPR-resident for whole kernel) ----
    bf16x8_t wf[6][8];
    {
        const unsigned short* Wd = whh + (size_t)dl*768*256;
        #pragma unroll
        for (int g = 0; g < 3; g++)
            #pragma unroll
            for (int jt = 0; jt < 2; jt++) {
                int n = g*256 + (2*wv + jt)*16 + col;
                const unsigned short* base = Wd + (size_t)n*256 + quad*8;
                #pragma unroll
                for (int kt = 0; kt < 8; kt++)
                    wf[g*2+jt][kt] = *(const bf16x8_t*)(base + kt*32);
            }
    }

    int j1[2]; j1[0] = (2*wv)*16 + col; j1[1] = (2*wv+1)*16 + col;
    float bhnv[2];
    bhnv[0] = bhn[dl*256 + j1[0]];
    bhnv[1] = bhn[dl*256 + j1[1]];

    int len_q[4];
    float hr[4][2];
    #pragma unroll
    for (int q = 0; q < 4; q++) {
        int bl = quad*4 + q;
        len_q[q] = lens[b0 + bl];
        #pragma unroll
        for (int jt = 0; jt < 2; jt++)
            hr[q][jt] = first ? 0.0f
                      : hstate[(size_t)(dir*64 + b0 + bl)*256 + j1[jt]];
    }

    for (int i = tid; i < 16*256; i += 512) {
        int bb = i >> 8, k = i & 255;
        float hv = first ? 0.0f : hstate[(size_t)(dir*64 + b0 + bb)*256 + k];
        hbuf[bb*HPAD + k] = f2bf(hv);
    }

    const int maxlen = lens[b0];   // batches sorted descending
    int tend = t0 + tc; if (tend > maxlen) tend = maxlen; if (tend < t0) tend = t0;
    const unsigned short* gi = dir ? gi_b : gi_f;
    unsigned short* hco = dir ? hbc : hfc;

    for (int t = t0; t < tend; t++) {
        __syncthreads();                       // hbuf stable (init / prev writes)
        f32x4_t acc[6];
        #pragma unroll
        for (int f = 0; f < 6; f++) acc[f] = (f32x4_t){0.f,0.f,0.f,0.f};
        #pragma unroll
        for (int kt = 0; kt < 8; kt++) {
            bf16x8_t a = *(const bf16x8_t*)(hbuf + col*HPAD + kt*32 + quad*8);
            #pragma unroll
            for (int f = 0; f < 6; f++)
                acc[f] = __builtin_amdgcn_mfma_f32_16x16x32_bf16(a, wf[f][kt], acc[f], 0, 0, 0);
        }
        // epilogue: gates + h update (gi loaded post-MFMA to cap VGPR pressure)
        #pragma unroll
        for (int q = 0; q < 4; q++) {
            int bl = quad*4 + q;
            int len = len_q[q];
            bool valid = t < len;
            float gv[3][2];
            if (layer == 0) {
                int p = dir ? (len - 1 - t) : t;
                if (p < 0) p = 0;
                int tok = x[(size_t)(b0 + bl)*SS + p];
                #pragma unroll
                for (int g = 0; g < 3; g++)
                    #pragma unroll
                    for (int jt = 0; jt < 2; jt++)
                        gv[g][jt] = bf2f(T0s[tok*768 + g*256 + j1[jt]]);
            } else {
                const unsigned short* gp = gi + ((size_t)(t - t0)*64 + b0 + bl)*768;
                #pragma unroll
                for (int g = 0; g < 3; g++)
                    #pragma unroll
                    for (int jt = 0; jt < 2; jt++)
                        gv[g][jt] = bf2f(gp[g*256 + j1[jt]]);
            }
            #pragma unroll
            for (int jt = 0; jt < 2; jt++) {
                float rr = 1.0f/(1.0f + __expf(-(acc[jt][q]   + gv[0][jt])));
                float zz = 1.0f/(1.0f + __expf(-(acc[2+jt][q] + gv[1][jt])));
                float ar = gv[2][jt] + rr*(acc[4+jt][q] + bhnv[jt]);
                float nn = 2.0f/(1.0f + __expf(-2.0f*ar)) - 1.0f;
                float hn = (1.0f - zz)*nn + zz*hr[q][jt];
                if (layer == 0) {
                    if (valid) {
                        hr[q][jt] = hn;
                        int tout = dir ? (len - 1 - t) : t;
                        h1out[((size_t)(b0+bl)*SS + tout)*512 + dir*256 + j1[jt]] = f2bf(hn);
                    }
                } else {
                    unsigned short hv = 0;
                    if (valid) { hr[q][jt] = hn; hv = f2bf(hn); }
                    hco[((size_t)(t - t0)*64 + b0 + bl)*256 + j1[jt]] = hv;
                }
            }
        }
        __syncthreads();                       // all waves done reading hbuf
        #pragma unroll
        for (int q = 0; q < 4; q++) {
            int bl = quad*4 + q;
            if (t < len_q[q]) {
                hbuf[bl*HPAD + j1[0]] = f2bf(hr[q][0]);
                hbuf[bl*HPAD + j1[1]] = f2bf(hr[q][1]);
            }
        }
    }

    // zero-fill chunk range where the whole block is past its max len
    if (layer == 1) {
        for (int t = tend; t < t0 + tc; t++) {
            #pragma unroll
            for (int q = 0; q < 4; q++) {
                int bl = quad*4 + q;
                size_t o = ((size_t)(t - t0)*64 + b0 + bl)*256;
                hco[o + j1[0]] = 0;
                hco[o + j1[1]] = 0;
            }
        }
    }
    // persist h state for next chunk
    #pragma unroll
    for (int q = 0; q < 4; q++) {
        int bl = quad*4 + q;
        hstate[(size_t)(dir*64 + b0 + bl)*256 + j1[0]] = hr[q][0];
        hstate[(size_t)(dir*64 + b0 + bl)*256 + j1[1]] = hr[q][1];
    }
}

// ---------------------------------------------------------------------------
// bf16 MFMA GEMM: C[crow(r), n] (+)= A[arow(r), :K] @ W[n, :K]^T + bias.
// amode: 0 r | 1 b*S+(t0+t) | 2 b*S+clamp(len-1-(t0+t),0)   [r=(t<<6)|b]
// cmode: 0 r | 1 b*S+(t0+t) | 2 b*S+(len-1-(t0+t)), store skipped if s<0
// ---------------------------------------------------------------------------
__global__ __launch_bounds__(256) void gemm_kernel(
    const unsigned short* A, const unsigned short* W, const float* bias,
    unsigned short* C, int N, int K, int amode, int cmode, int accum,
    const int* lens, int t0)
{
    int lane = threadIdx.x & 63;
    int wv = threadIdx.x >> 6;
    int n0 = blockIdx.x*64 + wv*16;
    int m0 = blockIdx.y*16;
    int rA = m0 + (lane & 15);
    int arow;
    if (amode == 0) arow = rA;
    else {
        int bb = rA & 63; int t = t0 + (rA >> 6);
        if (amode == 1) arow = bb*SS + t;
        else { int tt = lens[bb] - 1 - t; if (tt < 0) tt = 0; arow = bb*SS + tt; }
    }
    const unsigned short* Ap = A + (size_t)arow*K + (lane >> 4)*8;
    const unsigned short* Wp = W + (size_t)(n0 + (lane & 15))*K + (lane >> 4)*8;
    f32x4_t acc = {0.f, 0.f, 0.f, 0.f};
    for (int k0 = 0; k0 < K; k0 += 32) {
        bf16x8_t a = *(const bf16x8_t*)(Ap + k0);
        bf16x8_t w = *(const bf16x8_t*)(Wp + k0);
        acc = __builtin_amdgcn_mfma_f32_16x16x32_bf16(a, w, acc, 0, 0, 0);
    }
    int n = n0 + (lane & 15);
    float bv = bias ? bias[n] : 0.0f;
    int mbase = m0 + (lane >> 4)*4;
    for (int q = 0; q < 4; q++) {
        int r = mbase + q;
        size_t crow; bool valid = true;
        if (cmode == 0) crow = (size_t)r;
        else {
            int bb = r & 63; int t = t0 + (r >> 6);
            if (cmode == 1) crow = (size_t)bb*SS + t;
            else {
                int s = lens[bb] - 1 - t;
                if (s < 0) { valid = false; crow = 0; }
                else crow = (size_t)bb*SS + s;
            }
        }
        if (valid) {
            float v = acc[q] + bv;
            size_t idx = crow*(size_t)N + n;
            if (accum) v += bf2f(C[idx]);
            C[idx] = f2bf(v);
        }
    }
}

// ---------------------------------------------------------------------------
// BatchNorm stats (sum, sumsq per column) and apply(+leaky), in-place bf16
// ---------------------------------------------------------------------------
__global__ void bn_stats_kernel(const unsigned short* y, int N, int nslab, float* st)
{
    int gtid = blockIdx.x*blockDim.x + threadIdx.x;
    int c = gtid % N;
    int slab = gtid / N;
    const int M = 131072;
    float s = 0.f, s2 = 0.f;
    for (int r = slab; r < M; r += nslab) {
        float v = bf2f(y[(size_t)r*N + c]);
        s += v; s2 += v*v;
    }
    atomicAdd(&st[c], s);
    atomicAdd(&st[N + c], s2);
}

__global__ void bn_apply_kernel(unsigned short* y, const float* st,
                                const float* g, const float* be, int N)
{
    const int M = 131072;
    size_t total = (size_t)M*N;
    float invM = 1.0f / M;
    for (size_t i = blockIdx.x*(size_t)blockDim.x + threadIdx.x; i < total;
         i += (size_t)gridDim.x*blockDim.x) {
        int c = (int)(i % N);
        float mean = st[c]*invM;
        float var = fmaxf(st[N + c]*invM - mean*mean, 0.0f);
        float v = bf2f(y[i]);
        v = g[c]*(v - mean)*rsqrtf(var + 1e-5f) + be[c];
        y[i] = f2bf(v >= 0.f ? v : 0.01f*v);
    }
}

// ---------------------------------------------------------------------------
// Final dense(61) + softmax + mask. One wave per (b,t) row.
// ---------------------------------------------------------------------------
__constant__ int c_lo[21] = {0,0,4,10,12,14,16,18,20,24,26,29,35,36,37,39,43,49,53,57,58};
__constant__ int c_hi[21] = {0,4,10,12,14,16,18,20,24,26,29,35,36,37,39,43,49,53,57,58,60};

__global__ __launch_bounds__(256) void out_kernel(
    const unsigned short* o3, const float* w4, const float* b4,
    const int* x, const int* lens, float* out)
{
    __shared__ __align__(16) float w4t[128*64];   // transposed [k][v] padded to 64
    __shared__ float b4s[64];
    for (int i = threadIdx.x; i < 61*128; i += 256) {
        int v = i / 128, k = i % 128;
        w4t[k*64 + v] = w4[i];
    }
    if (threadIdx.x < 64) b4s[threadIdx.x] = threadIdx.x < 61 ? b4[threadIdx.x] : 0.f;
    __syncthreads();
    int wv = threadIdx.x >> 6;
    int lane = threadIdx.x & 63;
    int row = blockIdx.x*4 + wv;
    int b = row >> 11;
    int t = row & 2047;
    const unsigned int* o3r = (const unsigned int*)(o3 + (size_t)row*128);
    float dot;
    if (lane < 61) {
        dot = 0.f;
        for (int k2 = 0; k2 < 64; k2++) {
            float2 p = bfpair(o3r[k2]);
            dot += p.x * w4t[(2*k2)*64 + lane] + p.y * w4t[(2*k2 + 1)*64 + lane];
        }
        dot += b4s[lane];
    } else dot = -1e30f;
    float mx = dot;
    for (int off = 32; off >= 1; off >>= 1) mx = fmaxf(mx, __shfl_xor(mx, off, 64));
    float e = (lane < 61) ? __expf(dot - mx) : 0.f;
    float sm = e;
    for (int off = 32; off >= 1; off >>= 1) sm += __shfl_xor(sm, off, 64);
    float p = e / sm;
    if (lane < 61) {
        int tok = x[row];
        int len = lens[b];
        float maskv = NEGV;
        if (t < len && tok > 0 && lane >= c_lo[tok] && lane < c_hi[tok]) maskv = 0.f;
        out[(size_t)row*61 + lane] = p + maskv;
    }
}

// ---------------------------------------------------------------------------
__global__ void mask_only_kernel(const int* x, const int* lens, float* out)
{
    int row = blockIdx.x*blockDim.x + threadIdx.x;
    if (row >= 64*SS) return;
    int b = row >> 11, t = row & 2047;
    int tok = x[row], len = lens[b];
    float* o = out + (size_t)row*61;
    int lo = c_lo[tok], hi = c_hi[tok];
    for (int v = 0; v < 61; v++) {
        float m = NEGV;
        if (t < len && tok > 0 && v >= lo && v < hi) m = 0.f;
        o[v] = m;
    }
}

// ---------------------------------------------------------------------------
extern "C" void kernel_launch(void* const* d_in, const int* in_sizes, int n_in,
                              void* d_out, int out_size, void* d_ws, size_t ws_size,
                              hipStream_t stream)
{
    (void)in_sizes; (void)n_in; (void)out_size;
    const int*   x     = (const int*)  d_in[0];
    const int*   lens  = (const int*)  d_in[1];
    const float* emb   = (const float*)d_in[2];
    const float* wih0f = (const float*)d_in[3];
    const float* whh0f = (const float*)d_in[4];
    const float* bih0f = (const float*)d_in[5];
    const float* bhh0f = (const float*)d_in[6];
    const float* wih0b = (const float*)d_in[7];
    const float* whh0b = (const float*)d_in[8];
    const float* bih0b = (const float*)d_in[9];
    const float* bhh0b = (const float*)d_in[10];
    const float* wih1f = (const float*)d_in[11];
    const float* whh1f = (const float*)d_in[12];
    const float* bih1f = (const float*)d_in[13];
    const float* bhh1f = (const float*)d_in[14];
    const float* wih1b = (const float*)d_in[15];
    const float* whh1b = (const float*)d_in[16];
    const float* bih1b = (const float*)d_in[17];
    const float* bhh1b = (const float*)d_in[18];
    const float* w1  = (const float*)d_in[19];
    const float* b1  = (const float*)d_in[20];
    const float* g1  = (const float*)d_in[21];
    const float* be1 = (const float*)d_in[22];
    const float* w2  = (const float*)d_in[23];
    const float* b2  = (const float*)d_in[24];
    const float* g2  = (const float*)d_in[25];
    const float* be2 = (const float*)d_in[26];
    const float* w3  = (const float*)d_in[27];
    const float* b3  = (const float*)d_in[28];
    const float* g3  = (const float*)d_in[29];
    const float* be3 = (const float*)d_in[30];
    const float* w4  = (const float*)d_in[31];
    const float* b4  = (const float*)d_in[32];

    // ---- fixed region ----
    char* ws = (char*)d_ws;
    float*          T0     = (float*)(ws + 0);                 //   129,024
    unsigned short* whhbf  = (unsigned short*)(ws + 129024);   // 1,572,864
    unsigned short* wih1bf = (unsigned short*)(ws + 1701888);  // 1,572,864
    unsigned short* w123   = (unsigned short*)(ws + 3274752);  //   262,144
    float*          bias1  = (float*)(ws + 3536896);           //     6,144
    float*          bhn    = (float*)(ws + 3543040);           //     4,096
    float*          stats  = (float*)(ws + 3547136);           //     4,096
    float*          hstate = (float*)(ws + 3551232);           //   131,072
    const size_t OFF_H1  = 3682304;
    const size_t H1SZ    = 134217728ull;          // 64*2048*512 bf16
    const size_t Y1SZ    = 33554432ull;           // 131072*128 bf16
    const size_t OFF_Y1  = OFF_H1 + H1SZ;
    const size_t OFF_GI  = OFF_Y1 + Y1SZ;         // 171,454,464

    // per-TC chunk: gi 2 x TC*64*768*2 + hc 2 x TC*64*256*2 = TC*262144 bytes
    int TC = 0;
    for (int tc = 256; tc >= 32; tc >>= 1) {
        if (ws_size >= OFF_GI + (size_t)tc*262144ull) { TC = tc; break; }
    }
    if (TC == 0) { mask_only_kernel<<<512, 256, 0, stream>>>(x, lens, (float*)d_out); return; }

    unsigned short* h1    = (unsigned short*)(ws + OFF_H1);
    unsigned short* y1pre = (unsigned short*)(ws + OFF_Y1);
    unsigned short* gi_f  = (unsigned short*)(ws + OFF_GI);
    unsigned short* gi_b  = gi_f + (size_t)TC*64*768;
    unsigned short* hfc   = gi_b + (size_t)TC*64*768;
    unsigned short* hbc   = hfc  + (size_t)TC*64*256;
    unsigned short* y2    = h1;                          // h1 dead after chunk loop
    unsigned short* y3    = (unsigned short*)(ws + OFF_H1 + 67108864ull);

    zero_stats_kernel<<<4, 256, 0, stream>>>(stats);
    prep_kernel<<<1024, 256, 0, stream>>>(emb, wih0f, bih0f, bhh0f, wih0b, bih0b, bhh0b,
        whh0f, whh0b, whh1f, whh1b, wih1f, wih1b, bih1f, bhh1f, bih1b, bhh1b,
        w1, w2, w3, T0, whhbf, wih1bf, w123, bias1, bhn);
    init_y1_kernel<<<2048, 256, 0, stream>>>(y1pre, b1);

    // layer 0 scan (token-table gi), full sequence -> h1
    scan_mfma_kernel<<<8, 512, 0, stream>>>(x, lens, T0, nullptr, nullptr,
        whhbf, bhn, hstate, h1, nullptr, nullptr, 0, 0, SS, 1);

    // layer 1 chunks: gi gemms -> scan -> y1 accumulation gemms
    int NCH = SS / TC;
    for (int c = 0; c < NCH; c++) {
        int t0 = c*TC;
        gemm_kernel<<<dim3(12, TC*4), 256, 0, stream>>>(h1, wih1bf, bias1,
            gi_f, 768, 512, 1, 0, 0, lens, t0);
        gemm_kernel<<<dim3(12, TC*4), 256, 0, stream>>>(h1, wih1bf + 768*512, bias1 + 768,
            gi_b, 768, 512, 2, 0, 0, lens, t0);
        scan_mfma_kernel<<<8, 512, 0, stream>>>(x, lens, T0, gi_f, gi_b,
            whhbf, bhn, hstate, nullptr, hfc, hbc, 1, t0, TC, c == 0);
        gemm_kernel<<<dim3(2, TC*4), 256, 0, stream>>>(hfc, w123, nullptr,
            y1pre, 128, 256, 0, 1, 1, lens, t0);
        gemm_kernel<<<dim3(2, TC*4), 256, 0, stream>>>(hbc, w123 + 32768, nullptr,
            y1pre, 128, 256, 0, 2, 1, lens, t0);
    }

    // MLP: BN1 on y1pre, then dense2/BN2, dense3/BN3 (y2,y3 alias dead h1)
    bn_stats_kernel<<<512, 256, 0, stream>>>(y1pre, 128, 1024, stats);
    bn_apply_kernel<<<2048, 256, 0, stream>>>(y1pre, stats, g1, be1, 128);

    gemm_kernel<<<dim3(4, 8192), 256, 0, stream>>>(y1pre, w123 + 65536, b2,
        y2, 256, 128, 0, 0, 0, nullptr, 0);
    bn_stats_kernel<<<512, 256, 0, stream>>>(y2, 256, 512, stats + 256);
    bn_apply_kernel<<<4096, 256, 0, stream>>>(y2, stats + 256, g2, be2, 256);

    gemm_kernel<<<dim3(2, 8192), 256, 0, stream>>>(y2, w123 + 98304, b3,
        y3, 128, 256, 0, 0, 0, nullptr, 0);
    bn_stats_kernel<<<512, 256, 0, stream>>>(y3, 128, 1024, stats + 768);
    bn_apply_kernel<<<2048, 256, 0, stream>>>(y3, stats + 768, g3, be3, 128);

    // final dense(61) + softmax + mask
    out_kernel<<<32768, 256, 0, stream>>>(y3, w4, b4, x, lens, (float*)d_out);
}